// Round 1
// baseline (2241.562 us; speedup 1.0000x reference)
//
#include <hip/hip_runtime.h>
#include <hip/hip_bf16.h>
#include <stdint.h>

#define B_SZ 1024
#define FIN  4096
#define NMEM 256
#define NQK  16384   // 64 * 256

typedef __attribute__((ext_vector_type(8))) short short8;
typedef __attribute__((ext_vector_type(4))) float floatx4;

__device__ __forceinline__ ushort f2bf(float f) {
    uint32_t u = __float_as_uint(f);
    return (ushort)((u + 0x7fffu + ((u >> 16) & 1u)) >> 16);   // RNE
}
__device__ __forceinline__ float bf2f(ushort u) {
    return __uint_as_float(((uint32_t)u) << 16);
}

// ---------------- fp32 -> bf16, 8 elems/thread ----------------
__global__ void cvt_kernel(const float* __restrict__ src, ushort* __restrict__ dst, int n) {
    int i = (blockIdx.x * blockDim.x + threadIdx.x) * 8;
    if (i >= n) return;
    float4 f0 = *(const float4*)(src + i);
    float4 f1 = *(const float4*)(src + i + 4);
    uint4 o;
    o.x = (uint32_t)f2bf(f0.x) | ((uint32_t)f2bf(f0.y) << 16);
    o.y = (uint32_t)f2bf(f0.z) | ((uint32_t)f2bf(f0.w) << 16);
    o.z = (uint32_t)f2bf(f1.x) | ((uint32_t)f2bf(f1.y) << 16);
    o.w = (uint32_t)f2bf(f1.z) | ((uint32_t)f2bf(f1.w) << 16);
    *(uint4*)(dst + i) = o;
}

// ---------------- generic bf16-A x fp32-B MFMA GEMM ----------------
// A: [M x K] bf16 row-major.  B: [K x N] fp32 row-major (converted to bf16
// during LDS staging, stored transposed [n][k] in LDS).
// C = relu?(A@B + bias?) (+resid?), stored fp32 or bf16.
#define BM 128
#define BN 128
#define BKK 64
#define LDA 72   // bf16 elems per LDS row (64 + 8 pad -> 144 B, 16B aligned)
#define LDB 72

template<int RELU, int HASBIAS, int RESID, int OUTBF>
__global__ __launch_bounds__(256)
void gemm_k(const ushort* __restrict__ A, const float* __restrict__ B,
            const float* __restrict__ bias, const float* __restrict__ resid,
            void* __restrict__ Cout, int M, int N, int K)
{
    __shared__ ushort As[BM * LDA];
    __shared__ ushort Bs[BN * LDB];

    const int tid  = threadIdx.x;
    const int lane = tid & 63;
    const int wave = tid >> 6;
    const int wm = (wave >> 1) * 64;   // wave row offset in tile
    const int wn = (wave & 1) * 64;    // wave col offset in tile
    const int m0 = blockIdx.y * BM;
    const int n0 = blockIdx.x * BN;

    const int fr = lane & 15;   // fragment row/col
    const int fq = lane >> 4;   // quad 0..3

    floatx4 acc[4][4] = {};

    for (int k0 = 0; k0 < K; k0 += BKK) {
        __syncthreads();
        // ---- stage A tile: 128 rows x 64 bf16, 16B chunks, 4 per thread ----
        #pragma unroll
        for (int c = 0; c < 4; ++c) {
            int idx = c * 256 + tid;          // 0..1023
            int row = idx >> 3;               // 0..127
            int off = idx & 7;                // 0..7 (x8 bf16)
            *(uint4*)(&As[row * LDA + off * 8]) =
                *(const uint4*)(A + (size_t)(m0 + row) * K + k0 + off * 8);
        }
        // ---- stage B tile: 64k x 128n fp32 -> bf16, transposed to [n][k] ----
        #pragma unroll
        for (int p = 0; p < 8; ++p) {
            int idx = p * 256 + tid;          // 0..2047
            int nn = idx & 127;
            int kg = idx >> 7;                // 0..15, k = kg*4 .. kg*4+3
            const float* bp = B + (size_t)(k0 + kg * 4) * N + n0 + nn;
            float f0 = bp[0];
            float f1 = bp[N];
            float f2 = bp[2 * (size_t)N];
            float f3 = bp[3 * (size_t)N];
            ushort4 w;
            w.x = f2bf(f0); w.y = f2bf(f1); w.z = f2bf(f2); w.w = f2bf(f3);
            *(ushort4*)(&Bs[nn * LDB + kg * 4]) = w;
        }
        __syncthreads();

        // ---- 2 k-substeps of 32, 16 MFMAs each ----
        #pragma unroll
        for (int ks = 0; ks < 2; ++ks) {
            short8 a[4], b[4];
            #pragma unroll
            for (int i = 0; i < 4; ++i)
                a[i] = *(const short8*)(&As[(wm + i * 16 + fr) * LDA + ks * 32 + fq * 8]);
            #pragma unroll
            for (int i = 0; i < 4; ++i)
                b[i] = *(const short8*)(&Bs[(wn + i * 16 + fr) * LDB + ks * 32 + fq * 8]);
            #pragma unroll
            for (int mi = 0; mi < 4; ++mi)
                #pragma unroll
                for (int ni = 0; ni < 4; ++ni)
                    acc[mi][ni] = __builtin_amdgcn_mfma_f32_16x16x32_bf16(
                        a[mi], b[ni], acc[mi][ni], 0, 0, 0);
        }
    }

    // ---- epilogue: C/D layout col=lane&15, row=quad*4+reg ----
    #pragma unroll
    for (int mi = 0; mi < 4; ++mi) {
        #pragma unroll
        for (int ni = 0; ni < 4; ++ni) {
            #pragma unroll
            for (int r = 0; r < 4; ++r) {
                int gm = m0 + wm + mi * 16 + fq * 4 + r;
                int gn = n0 + wn + ni * 16 + fr;
                float val = acc[mi][ni][r];
                if (HASBIAS) val += bias[gn];
                if (RELU)    val = fmaxf(val, 0.0f);
                if (RESID)   val += resid[(size_t)gm * N + gn];
                if (OUTBF) ((ushort*)Cout)[(size_t)gm * N + gn] = f2bf(val);
                else       ((float*)Cout)[(size_t)gm * N + gn] = val;
            }
        }
    }
}

// ---------------- qbar[b,s] = (1/(256*8)) * sum_m XQr[b, m*64+s] ----------------
__global__ void qbar_kernel(const ushort* __restrict__ XQr, float* __restrict__ qbar) {
    int b = blockIdx.x;
    int s = threadIdx.x;  // 64 threads = 1 wave
    const ushort* p = XQr + (size_t)b * NQK + s;
    float sum = 0.0f;
    #pragma unroll 4
    for (int m = 0; m < NMEM; ++m) sum += bf2f(p[m * 64]);
    qbar[b * 64 + s] = sum * (1.0f / (NMEM * 8.0f));
}

// ---------------- s_pooled[b,n] = sum_s XKr[b, n*64+s] * qbar[b,s] -> bf16 ----------------
__global__ void spool_kernel(const ushort* __restrict__ XKr, const float* __restrict__ qbar,
                             ushort* __restrict__ spb) {
    int b = blockIdx.x;
    int n = threadIdx.x;  // 256 threads
    __shared__ float q[64];
    if (threadIdx.x < 64) q[threadIdx.x] = qbar[b * 64 + threadIdx.x];
    __syncthreads();
    const ushort* p = XKr + (size_t)b * NQK + n * 64;
    float sum = 0.0f;
    #pragma unroll
    for (int s = 0; s < 64; s += 4) {
        ushort4 u = *(const ushort4*)(p + s);
        sum += bf2f(u.x) * q[s] + bf2f(u.y) * q[s + 1]
             + bf2f(u.z) * q[s + 2] + bf2f(u.w) * q[s + 3];
    }
    spb[b * 256 + n] = f2bf(sum);
}

extern "C" void kernel_launch(void* const* d_in, const int* in_sizes, int n_in,
                              void* d_out, int out_size, void* d_ws, size_t ws_size,
                              hipStream_t stream) {
    const float* x  = (const float*)d_in[0];
    const float* Wq = (const float*)d_in[1];
    const float* bq = (const float*)d_in[2];
    const float* Wk = (const float*)d_in[3];
    const float* bk = (const float*)d_in[4];
    const float* v  = (const float*)d_in[5];
    const float* Wl = (const float*)d_in[6];
    const float* bl = (const float*)d_in[7];
    float* out = (float*)d_out;

    char* ws = (char*)d_ws;
    // layout (bytes):
    ushort* xb   = (ushort*)(ws + 0);          //  8 MB  x bf16 [1024,4096]
    ushort* vb   = (ushort*)(ws + 8388608);    //  2 MB  v bf16 [256,4096]
    ushort* XQr  = (ushort*)(ws + 10485760);   // 32 MB  relu(x@Wq+bq) bf16 [1024,16384]
    ushort* XKr  = (ushort*)(ws + 44040192);   // 32 MB  relu(x@Wk+bk) bf16
    float*  vWl  = (float*)(ws + 77594624);    //  4 MB  v@Wl fp32 [256,4096]
    float*  qbar = (float*)(ws + 81788928);    // 256 KB [1024,64]
    ushort* spb  = (ushort*)(ws + 82051072);   // 512 KB s_pooled bf16 [1024,256]

    // 1-2: convert x and v to bf16
    cvt_kernel<<<dim3((B_SZ * FIN) / 8 / 256), 256, 0, stream>>>(x, xb, B_SZ * FIN);
    cvt_kernel<<<dim3((NMEM * FIN) / 8 / 256), 256, 0, stream>>>(v, vb, NMEM * FIN);

    // 3-4: big projections with fused bias+relu, bf16 out
    gemm_k<1, 1, 0, 1><<<dim3(NQK / BN, B_SZ / BM), 256, 0, stream>>>(
        xb, Wq, bq, nullptr, XQr, B_SZ, NQK, FIN);
    gemm_k<1, 1, 0, 1><<<dim3(NQK / BN, B_SZ / BM), 256, 0, stream>>>(
        xb, Wk, bk, nullptr, XKr, B_SZ, NQK, FIN);

    // 5: vWl = v @ Wl  (fp32 out)
    gemm_k<0, 0, 0, 0><<<dim3(FIN / BN, NMEM / BM), 256, 0, stream>>>(
        vb, Wl, nullptr, nullptr, vWl, NMEM, FIN, FIN);

    // 6: qbar
    qbar_kernel<<<dim3(B_SZ), 64, 0, stream>>>(XQr, qbar);
    // 7: s_pooled
    spool_kernel<<<dim3(B_SZ), 256, 0, stream>>>(XKr, qbar, spb);

    // 8: out = x + spb @ vWl + bl   (fp32 out, residual fused)
    gemm_k<0, 1, 1, 0><<<dim3(FIN / BN, B_SZ / BM), 256, 0, stream>>>(
        spb, vWl, bl, x, out, B_SZ, FIN, NMEM);
}

// Round 2
// 1031.880 us; speedup vs baseline: 2.1723x; 2.1723x over previous
//
#include <hip/hip_runtime.h>
#include <hip/hip_bf16.h>
#include <stdint.h>

#define B_SZ 1024
#define FIN  4096
#define NMEM 256
#define NQK  16384   // 64 * 256

typedef __attribute__((ext_vector_type(8))) short short8;
typedef __attribute__((ext_vector_type(4))) float floatx4;

__device__ __forceinline__ ushort f2bf(float f) {
    uint32_t u = __float_as_uint(f);
    return (ushort)((u + 0x7fffu + ((u >> 16) & 1u)) >> 16);   // RNE
}
__device__ __forceinline__ float bf2f(ushort u) {
    return __uint_as_float(((uint32_t)u) << 16);
}

// async global->LDS, 16B per lane; lptr must be wave-uniform, HW adds lane*16
__device__ __forceinline__ void gl2lds16(const void* g, void* l) {
    __builtin_amdgcn_global_load_lds(
        (const __attribute__((address_space(1))) void*)g,
        (__attribute__((address_space(3))) void*)l, 16, 0, 0);
}

// ---------------- fp32 -> bf16, 8 elems/thread ----------------
__global__ void cvt_kernel(const float* __restrict__ src, ushort* __restrict__ dst, int n) {
    int i = (blockIdx.x * blockDim.x + threadIdx.x) * 8;
    if (i >= n) return;
    float4 f0 = *(const float4*)(src + i);
    float4 f1 = *(const float4*)(src + i + 4);
    uint4 o;
    o.x = (uint32_t)f2bf(f0.x) | ((uint32_t)f2bf(f0.y) << 16);
    o.y = (uint32_t)f2bf(f0.z) | ((uint32_t)f2bf(f0.w) << 16);
    o.z = (uint32_t)f2bf(f1.x) | ((uint32_t)f2bf(f1.y) << 16);
    o.w = (uint32_t)f2bf(f1.z) | ((uint32_t)f2bf(f1.w) << 16);
    *(uint4*)(dst + i) = o;
}

// ---------------- fp32 [4096 k][NFULL n] -> bf16 [n][k], column chunk at n0 ----------------
// grid: (Nc/64, 4096/64), 256 threads. dst is [Nc][4096] bf16.
__global__ __launch_bounds__(256)
void transT_kernel(const float* __restrict__ src, ushort* __restrict__ dst,
                   int NFULL, int n0) {
    __shared__ float lds[64 * 65];
    const int tid = threadIdx.x;
    const int nc0 = blockIdx.x * 64;   // local n of tile
    const int k0  = blockIdx.y * 64;
    #pragma unroll
    for (int p = 0; p < 4; ++p) {
        int idx = p * 256 + tid;          // 0..1023
        int krow = idx >> 4;              // 0..63
        int c4 = (idx & 15) * 4;          // n-local, x4
        float4 v = *(const float4*)(src + (size_t)(k0 + krow) * NFULL + n0 + nc0 + c4);
        lds[krow * 65 + c4 + 0] = v.x;
        lds[krow * 65 + c4 + 1] = v.y;
        lds[krow * 65 + c4 + 2] = v.z;
        lds[krow * 65 + c4 + 3] = v.w;
    }
    __syncthreads();
    #pragma unroll
    for (int p = 0; p < 2; ++p) {
        int idx = p * 256 + tid;          // 0..511
        int nrow = idx >> 3;              // 0..63
        int c8 = (idx & 7) * 8;           // k-local, x8
        ushort t[8];
        #pragma unroll
        for (int j = 0; j < 8; ++j) t[j] = f2bf(lds[(c8 + j) * 65 + nrow]);
        uint4 o;
        o.x = (uint32_t)t[0] | ((uint32_t)t[1] << 16);
        o.y = (uint32_t)t[2] | ((uint32_t)t[3] << 16);
        o.z = (uint32_t)t[4] | ((uint32_t)t[5] << 16);
        o.w = (uint32_t)t[6] | ((uint32_t)t[7] << 16);
        *(uint4*)(dst + (size_t)(nc0 + nrow) * 4096 + k0 + c8) = o;
    }
}

// ---------------- bf16 A [M][K] x bf16 B^T [N][K] MFMA GEMM, m97-style ----------------
// global_load_lds staging, XOR-swizzled 16B chunk placement (conflict-free frag reads).
// C = relu?(A@B + bias?) (+resid?) into Cout with row stride ldc.
template<int RELU, int HASBIAS, int RESID, int OUTBF>
__global__ __launch_bounds__(256)
void gemm_bf(const ushort* __restrict__ A, const ushort* __restrict__ Bt,
             const float* __restrict__ bias, const float* __restrict__ resid,
             void* __restrict__ Cout, int ldc, int M, int K)
{
    __shared__ __align__(16) ushort As[128 * 64];
    __shared__ __align__(16) ushort Bs[128 * 64];

    const int tid  = threadIdx.x;
    const int lane = tid & 63;
    const int wave = tid >> 6;
    const int wm = (wave >> 1) * 64;
    const int wn = (wave & 1) * 64;
    const int m0 = blockIdx.y * 128;
    const int n0 = blockIdx.x * 128;

    const int fr = lane & 15;
    const int fq = lane >> 4;

    floatx4 acc[4][4] = {};

    for (int k0 = 0; k0 < K; k0 += 64) {
        __syncthreads();
        // stage A+B: 1024 chunks of 16B each; chunk id -> row=id>>3, pos=id&7,
        // global chunk c = pos ^ (row&7) (XOR swizzle)
        #pragma unroll
        for (int i = 0; i < 4; ++i) {
            int id = i * 256 + wave * 64 + lane;
            int row = id >> 3, pos = id & 7;
            int c = pos ^ (row & 7);
            gl2lds16(A + (size_t)(m0 + row) * K + k0 + c * 8,
                     &As[(i * 256 + wave * 64) * 8]);
        }
        #pragma unroll
        for (int i = 0; i < 4; ++i) {
            int id = i * 256 + wave * 64 + lane;
            int row = id >> 3, pos = id & 7;
            int c = pos ^ (row & 7);
            gl2lds16(Bt + (size_t)(n0 + row) * K + k0 + c * 8,
                     &Bs[(i * 256 + wave * 64) * 8]);
        }
        __syncthreads();

        #pragma unroll
        for (int ks = 0; ks < 2; ++ks) {
            short8 a[4], b[4];
            #pragma unroll
            for (int i = 0; i < 4; ++i) {
                int row = wm + i * 16 + fr;
                int p = (ks * 4 + fq) ^ (row & 7);
                a[i] = *(const short8*)(&As[row * 64 + p * 8]);
            }
            #pragma unroll
            for (int i = 0; i < 4; ++i) {
                int row = wn + i * 16 + fr;
                int p = (ks * 4 + fq) ^ (row & 7);
                b[i] = *(const short8*)(&Bs[row * 64 + p * 8]);
            }
            #pragma unroll
            for (int mi = 0; mi < 4; ++mi)
                #pragma unroll
                for (int ni = 0; ni < 4; ++ni)
                    acc[mi][ni] = __builtin_amdgcn_mfma_f32_16x16x32_bf16(
                        a[mi], b[ni], acc[mi][ni], 0, 0, 0);
        }
    }

    // epilogue: C/D layout col=lane&15, row=quad*4+reg
    #pragma unroll
    for (int mi = 0; mi < 4; ++mi) {
        #pragma unroll
        for (int ni = 0; ni < 4; ++ni) {
            #pragma unroll
            for (int r = 0; r < 4; ++r) {
                int gm = m0 + wm + mi * 16 + fq * 4 + r;
                int gn = n0 + wn + ni * 16 + fr;
                float val = acc[mi][ni][r];
                if (HASBIAS) val += bias[gn];
                if (RELU)    val = fmaxf(val, 0.0f);
                if (RESID)   val += resid[(size_t)gm * ldc + gn];
                if (OUTBF) ((ushort*)Cout)[(size_t)gm * ldc + gn] = f2bf(val);
                else       ((float*)Cout)[(size_t)gm * ldc + gn] = val;
            }
        }
    }
}

// ---------------- bf16-A x fp32-B GEMM (convert-in-LDS path, round-1 proven) ----------------
#define BM 128
#define BN 128
#define BKK 64
#define LDA 72
#define LDB 72

template<int RELU, int HASBIAS, int RESID, int OUTBF>
__global__ __launch_bounds__(256)
void gemm_k(const ushort* __restrict__ A, const float* __restrict__ B,
            const float* __restrict__ bias, const float* __restrict__ resid,
            void* __restrict__ Cout, int M, int N, int K)
{
    __shared__ ushort As[BM * LDA];
    __shared__ ushort Bs[BN * LDB];

    const int tid  = threadIdx.x;
    const int lane = tid & 63;
    const int wave = tid >> 6;
    const int wm = (wave >> 1) * 64;
    const int wn = (wave & 1) * 64;
    const int m0 = blockIdx.y * BM;
    const int n0 = blockIdx.x * BN;

    const int fr = lane & 15;
    const int fq = lane >> 4;

    floatx4 acc[4][4] = {};

    for (int k0 = 0; k0 < K; k0 += BKK) {
        __syncthreads();
        #pragma unroll
        for (int c = 0; c < 4; ++c) {
            int idx = c * 256 + tid;
            int row = idx >> 3;
            int off = idx & 7;
            *(uint4*)(&As[row * LDA + off * 8]) =
                *(const uint4*)(A + (size_t)(m0 + row) * K + k0 + off * 8);
        }
        #pragma unroll
        for (int p = 0; p < 8; ++p) {
            int idx = p * 256 + tid;
            int nn = idx & 127;
            int kg = idx >> 7;
            const float* bp = B + (size_t)(k0 + kg * 4) * N + n0 + nn;
            float f0 = bp[0];
            float f1 = bp[N];
            float f2 = bp[2 * (size_t)N];
            float f3 = bp[3 * (size_t)N];
            ushort4 w;
            w.x = f2bf(f0); w.y = f2bf(f1); w.z = f2bf(f2); w.w = f2bf(f3);
            *(ushort4*)(&Bs[nn * LDB + kg * 4]) = w;
        }
        __syncthreads();

        #pragma unroll
        for (int ks = 0; ks < 2; ++ks) {
            short8 a[4], b[4];
            #pragma unroll
            for (int i = 0; i < 4; ++i)
                a[i] = *(const short8*)(&As[(wm + i * 16 + fr) * LDA + ks * 32 + fq * 8]);
            #pragma unroll
            for (int i = 0; i < 4; ++i)
                b[i] = *(const short8*)(&Bs[(wn + i * 16 + fr) * LDB + ks * 32 + fq * 8]);
            #pragma unroll
            for (int mi = 0; mi < 4; ++mi)
                #pragma unroll
                for (int ni = 0; ni < 4; ++ni)
                    acc[mi][ni] = __builtin_amdgcn_mfma_f32_16x16x32_bf16(
                        a[mi], b[ni], acc[mi][ni], 0, 0, 0);
        }
    }

    #pragma unroll
    for (int mi = 0; mi < 4; ++mi) {
        #pragma unroll
        for (int ni = 0; ni < 4; ++ni) {
            #pragma unroll
            for (int r = 0; r < 4; ++r) {
                int gm = m0 + wm + mi * 16 + fq * 4 + r;
                int gn = n0 + wn + ni * 16 + fr;
                float val = acc[mi][ni][r];
                if (HASBIAS) val += bias[gn];
                if (RELU)    val = fmaxf(val, 0.0f);
                if (RESID)   val += resid[(size_t)gm * N + gn];
                if (OUTBF) ((ushort*)Cout)[(size_t)gm * N + gn] = f2bf(val);
                else       ((float*)Cout)[(size_t)gm * N + gn] = val;
            }
        }
    }
}

// ---------------- qbar[b,s] = (1/(256*8)) * sum_m XQr[b, m*64+s] ----------------
__global__ void qbar_kernel(const ushort* __restrict__ XQr, float* __restrict__ qbar) {
    int b = blockIdx.x;
    int s = threadIdx.x;  // 64 threads = 1 wave
    const ushort* p = XQr + (size_t)b * NQK + s;
    float sum = 0.0f;
    #pragma unroll 4
    for (int m = 0; m < NMEM; ++m) sum += bf2f(p[m * 64]);
    qbar[b * 64 + s] = sum * (1.0f / (NMEM * 8.0f));
}

// ---------------- s_pooled[b,n] = sum_s XKr[b, n*64+s] * qbar[b,s] -> bf16 ----------------
__global__ void spool_kernel(const ushort* __restrict__ XKr, const float* __restrict__ qbar,
                             ushort* __restrict__ spb) {
    int b = blockIdx.x;
    int n = threadIdx.x;  // 256 threads
    __shared__ float q[64];
    if (threadIdx.x < 64) q[threadIdx.x] = qbar[b * 64 + threadIdx.x];
    __syncthreads();
    const ushort* p = XKr + (size_t)b * NQK + n * 64;
    float sum = 0.0f;
    #pragma unroll
    for (int s = 0; s < 64; s += 4) {
        ushort4 u = *(const ushort4*)(p + s);
        sum += bf2f(u.x) * q[s] + bf2f(u.y) * q[s + 1]
             + bf2f(u.z) * q[s + 2] + bf2f(u.w) * q[s + 3];
    }
    spb[b * 256 + n] = f2bf(sum);
}

extern "C" void kernel_launch(void* const* d_in, const int* in_sizes, int n_in,
                              void* d_out, int out_size, void* d_ws, size_t ws_size,
                              hipStream_t stream) {
    const float* x  = (const float*)d_in[0];
    const float* Wq = (const float*)d_in[1];
    const float* bq = (const float*)d_in[2];
    const float* Wk = (const float*)d_in[3];
    const float* bk = (const float*)d_in[4];
    const float* v  = (const float*)d_in[5];
    const float* Wl = (const float*)d_in[6];
    const float* bl = (const float*)d_in[7];
    float* out = (float*)d_out;

    const size_t MB = 1ull << 20;
    char* ws = (char*)d_ws;
    ushort* xb   = (ushort*)(ws + 0);        //  8 MB  x bf16 [1024][4096]
    ushort* XQr  = (ushort*)(ws + 8 * MB);   // 32 MB  relu(x@Wq+bq) bf16 [1024][16384]
    ushort* XKr  = (ushort*)(ws + 40 * MB);  // 32 MB
    float*  qbar = (float*)(ws + 72 * MB);   // 256 KB [1024][64]
    ushort* spb  = (ushort*)(ws + 73 * MB);  // 512 KB s_pooled bf16 [1024][256]
    ushort* p2b  = (ushort*)(ws + 74 * MB);  //  8 MB  (spb@v) bf16 [1024][4096]
    ushort* WT   = (ushort*)(ws + 82 * MB);  // 64 MB  transposed bf16 weight chunk [8192][4096]

    // x -> bf16
    cvt_kernel<<<dim3((B_SZ * FIN) / 8 / 256), 256, 0, stream>>>(x, xb, B_SZ * FIN);

    // Q projection, two N-chunks of 8192 (WT buffer reused)
    for (int c = 0; c < 2; ++c) {
        int n0 = c * 8192;
        transT_kernel<<<dim3(8192 / 64, FIN / 64), 256, 0, stream>>>(Wq, WT, NQK, n0);
        gemm_bf<1, 1, 0, 1><<<dim3(8192 / 128, B_SZ / 128), 256, 0, stream>>>(
            xb, WT, bq + n0, nullptr, XQr + n0, NQK, B_SZ, FIN);
    }
    qbar_kernel<<<dim3(B_SZ), 64, 0, stream>>>(XQr, qbar);

    // K projection
    for (int c = 0; c < 2; ++c) {
        int n0 = c * 8192;
        transT_kernel<<<dim3(8192 / 64, FIN / 64), 256, 0, stream>>>(Wk, WT, NQK, n0);
        gemm_bf<1, 1, 0, 1><<<dim3(8192 / 128, B_SZ / 128), 256, 0, stream>>>(
            xb, WT, bk + n0, nullptr, XKr + n0, NQK, B_SZ, FIN);
    }
    spool_kernel<<<dim3(B_SZ), 256, 0, stream>>>(XKr, qbar, spb);

    // p2 = spb @ v  (fp32-B path, K=256), bf16 out
    gemm_k<0, 0, 0, 1><<<dim3(FIN / BN, B_SZ / BM), 256, 0, stream>>>(
        spb, v, nullptr, nullptr, p2b, B_SZ, FIN, NMEM);

    // WlT (32 MB into WT buffer), then out = x + p2 @ Wl + bl
    transT_kernel<<<dim3(FIN / 64, FIN / 64), 256, 0, stream>>>(Wl, WT, FIN, 0);
    gemm_bf<0, 1, 1, 0><<<dim3(FIN / 128, B_SZ / 128), 256, 0, stream>>>(
        p2b, WT, bl, x, out, FIN, B_SZ, FIN);
}